// Round 15
// baseline (35.656 us; speedup 1.0000x reference)
//
#include <hip/hip_runtime.h>
#include <hip/hip_bf16.h>
#include <math.h>

#define NN 8192
#define DD 64
// Block tile 128x64 (4 waves as 2x2 of 64x32 wave tiles), TPB=16 along bj.
#define BI_MAX 64               // block-rows (128 rows each)
#define BJ_MAX 128              // block-cols (64 cols each)
#define TRI_N 4160              // per sym combo: sum_{bi<64}(128-2bi)
#define T1B TRI_N               // end of XX
#define T2B (2*TRI_N)           // 8320: end of ZZ
#define TILES_TOTAL 16512       // 2*4160 + 64*128
#define TPB 16
#define NBLOCKS (TILES_TOTAL / TPB)   // 1032
#define NSLOT 32
#define SLOT_STRIDE 16          // floats -> 64B per slot

// Fragment-order layout: panel p = 16 source rows; chunk lane L holds
// row (p*16 + (L&15)), bf16 elems [ks*32 + (L>>4)*8, +8).
// Element offset of chunk: p*1024 + ks*512 + L*8   (bf16 elements)
#define PANEL_ELEMS 1024        // 16 rows * 64 elems

typedef __bf16 bf16x8 __attribute__((ext_vector_type(8)));
typedef float f32x4 __attribute__((ext_vector_type(4)));

#if defined(__has_builtin)
#if __has_builtin(__builtin_amdgcn_exp2f)
#define EXP2F __builtin_amdgcn_exp2f
#endif
#endif
#ifndef EXP2F
#define EXP2F exp2f
#endif

// ws layout:
//   [0,        1048576)  XbF bf16 [512 panels][2 ks][64 lanes][8]  (fragment order)
//   [1048576,  2097152)  ZbF bf16 same
//   [2097152, +32768)    na  f32  [8192]   ( = -log2(e) * ||x_i||^2 )
//   [+32768,  +65536)    nb  f32  [8192]
//   [+65536,  +71680)    partial f32 [3*NSLOT*SLOT_STRIDE]

__global__ __launch_bounds__(256) void prep_kernel(
        const float* __restrict__ X, const float* __restrict__ Z,
        __hip_bfloat16* __restrict__ XbF, __hip_bfloat16* __restrict__ ZbF,
        float* __restrict__ na, float* __restrict__ nb,
        float* __restrict__ partial) {
    int tid = threadIdx.x;
    int gw = blockIdx.x * 4 + (tid >> 6);    // panel index in [0, 1024)
    int lane = tid & 63;
    int lm = lane & 15, lk = lane >> 4;
    const float* src = (gw < 512) ? X : Z;
    __hip_bfloat16* dst = (gw < 512) ? XbF : ZbF;
    float* nrm = (gw < 512) ? na : nb;
    int p = (gw < 512) ? gw : gw - 512;
    int row = p * 16 + lm;

    float s = 0.f;
    #pragma unroll
    for (int ks = 0; ks < 2; ++ks) {
        const float4* q = (const float4*)(src + (size_t)row * DD + ks * 32 + lk * 8);
        float4 u = q[0], v = q[1];
        float w[8] = {u.x, u.y, u.z, u.w, v.x, v.y, v.z, v.w};
        unsigned int h[8];
        #pragma unroll
        for (int r = 0; r < 8; ++r) {
            __hip_bfloat16 b = __float2bfloat16(w[r]);
            h[r] = *(unsigned short*)&b;
            float xr = __bfloat162float(b);
            s = fmaf(xr, xr, s);
        }
        uint4 pk;
        pk.x = h[0] | (h[1] << 16); pk.y = h[2] | (h[3] << 16);
        pk.z = h[4] | (h[5] << 16); pk.w = h[6] | (h[7] << 16);
        *(uint4*)(dst + (size_t)p * PANEL_ELEMS + ks * 512 + lane * 8) = pk;
    }
    s += __shfl_xor(s, 16, 64);
    s += __shfl_xor(s, 32, 64);
    if (lk == 0) nrm[row] = -1.4426950408889634f * s;

    if (blockIdx.x == 0) {
        for (int i = tid; i < 3 * NSLOT * SLOT_STRIDE; i += 256) partial[i] = 0.f;
    }
}

// R14's structure + DEPTH-2 B prefetch: 3 rotating B buffers (indices fold
// to constants under the full unroll), B(t+2) issued in body t. Doubles the
// prefetch->use window from ~220cy (< loaded-L2 latency) to ~450cy. Only
// +16 VGPR, so 3 waves/SIMD occupancy is held constant -- single variable.
__global__ __launch_bounds__(256) void mmd_kernel(
        const __hip_bfloat16* __restrict__ XbFh, const __hip_bfloat16* __restrict__ ZbFh,
        const float* __restrict__ na, const float* __restrict__ nb,
        float* __restrict__ partial) {
    int tid = threadIdx.x;
    int wave = tid >> 6, lane = tid & 63;
    int wr = wave >> 1, wc = wave & 1;
    int lm = lane & 15;   // frag row (within 16) / C col
    int lk = lane >> 4;   // k-group of 8 / C row group of 4
    __shared__ float wsum[4];
    const float C2 = 2.8853900817779268f;  // 2*log2(e)

    // ---- map block's first tile (once) ----
    int t0 = blockIdx.x * TPB;
    int combo, bi, bj;
    if (t0 < T2B) {
        combo = (t0 < T1B) ? 0 : 1;
        int tt = t0 - (combo ? T1B : 0);
        int rr = (int)((129.0f - sqrtf(16641.0f - 4.0f * (float)tt)) * 0.5f);
        rr = rr < 0 ? 0 : (rr > 63 ? 63 : rr);
        while (rr > 0 && rr * (129 - rr) > tt) --rr;
        while ((rr + 1) * (128 - rr) <= tt) ++rr;
        bi = rr;
        bj = 2 * rr + (tt - rr * (129 - rr));
    } else {
        combo = 2;
        int rem = t0 - T2B;
        bi = rem >> 7;
        bj = rem & 127;
    }
    const bool sym = (combo != 2);
    const __bf16 *A, *B;
    const float *sa, *sb;
    const __bf16* XbF = (const __bf16*)XbFh;
    const __bf16* ZbF = (const __bf16*)ZbFh;
    if (combo == 0)      { A = XbF; B = XbF; sa = na; sb = na; }
    else if (combo == 1) { A = ZbF; B = ZbF; sa = nb; sb = nb; }
    else                 { A = XbF; B = ZbF; sa = na; sb = nb; }

    // ---- A fragments + row norms for current bi ----
    bf16x8 af[2][4];
    float nav[4][4], navrtmax[4], navmax;
    {
        int pA = bi * 8 + wr * 4;
        #pragma unroll
        for (int ks = 0; ks < 2; ++ks)
            #pragma unroll
            for (int rt = 0; rt < 4; ++rt)
                af[ks][rt] = *(const bf16x8*)(A + (size_t)(pA + rt) * PANEL_ELEMS + ks * 512 + lane * 8);
        int row0 = bi * 128 + wr * 64;
        #pragma unroll
        for (int rt = 0; rt < 4; ++rt) {
            #pragma unroll
            for (int r = 0; r < 4; ++r) nav[rt][r] = sa[row0 + rt * 16 + lk * 4 + r];
            navrtmax[rt] = fmaxf(fmaxf(nav[rt][0], nav[rt][1]), fmaxf(nav[rt][2], nav[rt][3]));
        }
        navmax = fmaxf(fmaxf(navrtmax[0], navrtmax[1]), fmaxf(navrtmax[2], navrtmax[3]));
    }

// Prefetch B tile for column BJ_ into rotating buffer slot S (0..2).
#define PF_B(S, BJ_)                                                                 \
    {                                                                                \
        int pB_ = (BJ_) * 4 + wc * 2;                                                \
        _Pragma("unroll")                                                            \
        for (int ks = 0; ks < 2; ++ks)                                               \
            for (int ct = 0; ct < 2; ++ct)                                           \
                bufB[S][ks][ct] = *(const bf16x8*)(B + (size_t)(pB_ + ct) * PANEL_ELEMS + ks * 512 + lane * 8); \
        int col0_ = (BJ_) * 64 + wc * 32;                                            \
        _Pragma("unroll")                                                            \
        for (int ct = 0; ct < 2; ++ct) bufNb[S][ct] = sb[col0_ + ct * 16 + lm];      \
    }

    // ---- prologue: prefetch tiles t0 (slot 0) and t0+1 (slot 1) ----
    bf16x8 bufB[3][2][2];
    float bufNb[3][2];
    PF_B(0, bj)
    int pbi = bi, pbj = bj;        // prefetch coords, currently at t0
    {
        pbj = pbj + 1;
        if (pbj == BJ_MAX) { pbi = pbi + 1; pbj = sym ? 2 * pbi : 0; }
        PF_B(1, pbj)
    }

    float lsum = 0.f;

    #pragma unroll
    for (int it = 0; it < TPB; ++it) {
        const int cur = it % 3;
        const bool last = (it + 1 == TPB);
        int row0 = bi * 128 + wr * 64;
        int col0 = bj * 64 + wc * 32;
        bool above = sym && (col0 >= row0 + 64);     // whole tile strictly above diag
        bool elemw = sym && !above;                  // per-element weights
        float tileScale = above ? 2.f : 1.f;

        // ---- depth-2 prefetch: issue B(t+2) into slot (it+2)%3 ----
        if (it + 2 < TPB) {
            pbj = pbj + 1;
            if (pbj == BJ_MAX) { pbi = pbi + 1; pbj = sym ? 2 * pbi : 0; }
            PF_B((it + 2) % 3, pbj)
        }
        // Fence: prefetch loads must ISSUE here, before the MFMA cluster.
        __builtin_amdgcn_sched_barrier(0);

        // ---- MFMA ----
        f32x4 acc[4][2] = {};
        #pragma unroll
        for (int ks = 0; ks < 2; ++ks)
            #pragma unroll
            for (int rt = 0; rt < 4; ++rt)
                #pragma unroll
                for (int ct = 0; ct < 2; ++ct)
                    acc[rt][ct] = __builtin_amdgcn_mfma_f32_16x16x32_bf16(
                        af[ks][rt], bufB[cur][ks][ct], acc[rt][ct], 0, 0, 0);

        // ---- tile-level gate: one branch for fully-closed tiles ----
        float gmax = fmaxf(fmaxf(acc[0][0][0], acc[0][0][1]), fmaxf(acc[0][0][2], acc[0][0][3]));
        #pragma unroll
        for (int rt = 0; rt < 4; ++rt)
            #pragma unroll
            for (int ct = 0; ct < 2; ++ct)
                if (rt || ct) {
                    float m = fmaxf(fmaxf(acc[rt][ct][0], acc[rt][ct][1]),
                                    fmaxf(acc[rt][ct][2], acc[rt][ct][3]));
                    gmax = fmaxf(gmax, m);
                }
        float nbmax = fmaxf(bufNb[cur][0], bufNb[cur][1]);
        float tileBound = fmaf(gmax, C2, navmax + nbmax);
        if (__any(tileBound > -30.f)) {
            // ---- per-frag gated epilogue (rare: diag-adjacent tiles) ----
            #pragma unroll
            for (int rt = 0; rt < 4; ++rt) {
                #pragma unroll
                for (int ct = 0; ct < 2; ++ct) {
                    float fm = fmaxf(fmaxf(acc[rt][ct][0], acc[rt][ct][1]),
                                     fmaxf(acc[rt][ct][2], acc[rt][ct][3]));
                    float fb = fmaf(fm, C2, navrtmax[rt] + bufNb[cur][ct]);
                    if (__any(fb > -30.f)) {
                        float base = bufNb[cur][ct];
                        float a0 = fmaf(acc[rt][ct][0], C2, nav[rt][0] + base);
                        float a1 = fmaf(acc[rt][ct][1], C2, nav[rt][1] + base);
                        float a2 = fmaf(acc[rt][ct][2], C2, nav[rt][2] + base);
                        float a3 = fmaf(acc[rt][ct][3], C2, nav[rt][3] + base);
                        float e0 = EXP2F(fminf(a0, 0.f));
                        float e1 = EXP2F(fminf(a1, 0.f));
                        float e2 = EXP2F(fminf(a2, 0.f));
                        float e3 = EXP2F(fminf(a3, 0.f));
                        if (elemw) {
                            int gcol = col0 + ct * 16 + lm;
                            int gr = row0 + rt * 16 + lk * 4;
                            e0 *= (gr + 0 < gcol) ? 2.f : ((gr + 0 == gcol) ? 1.f : 0.f);
                            e1 *= (gr + 1 < gcol) ? 2.f : ((gr + 1 == gcol) ? 1.f : 0.f);
                            e2 *= (gr + 2 < gcol) ? 2.f : ((gr + 2 == gcol) ? 1.f : 0.f);
                            e3 *= (gr + 3 < gcol) ? 2.f : ((gr + 3 == gcol) ? 1.f : 0.f);
                            lsum += (e0 + e1) + (e2 + e3);
                        } else {
                            lsum += tileScale * ((e0 + e1) + (e2 + e3));
                        }
                    }
                }
            }
        }

        // ---- step compute coords; reload A on row change ----
        int nbi = bi, nbj = bj;
        if (!last) {
            nbj = bj + 1;
            if (nbj == BJ_MAX) { nbi = bi + 1; nbj = sym ? 2 * nbi : 0; }
            if (nbi != bi) {
                int npA = nbi * 8 + wr * 4;
                #pragma unroll
                for (int ks = 0; ks < 2; ++ks)
                    #pragma unroll
                    for (int rt = 0; rt < 4; ++rt)
                        af[ks][rt] = *(const bf16x8*)(A + (size_t)(npA + rt) * PANEL_ELEMS + ks * 512 + lane * 8);
                int nrow0 = nbi * 128 + wr * 64;
                #pragma unroll
                for (int rt = 0; rt < 4; ++rt) {
                    #pragma unroll
                    for (int r = 0; r < 4; ++r) nav[rt][r] = sa[nrow0 + rt * 16 + lk * 4 + r];
                    navrtmax[rt] = fmaxf(fmaxf(nav[rt][0], nav[rt][1]), fmaxf(nav[rt][2], nav[rt][3]));
                }
                navmax = fmaxf(fmaxf(navrtmax[0], navrtmax[1]), fmaxf(navrtmax[2], navrtmax[3]));
                __builtin_amdgcn_sched_barrier(0);
            }
        }
        bi = nbi; bj = nbj;
    }
#undef PF_B

    // ---- single flush, spread over cache-line slots ----
    #pragma unroll
    for (int off = 32; off; off >>= 1) lsum += __shfl_xor(lsum, off, 64);
    if (lane == 0) wsum[wave] = lsum;
    __syncthreads();
    if (tid == 0) {
        float s = (wsum[0] + wsum[1]) + (wsum[2] + wsum[3]);
        int slot = combo * NSLOT + (blockIdx.x & (NSLOT - 1));
        atomicAdd(&partial[slot * SLOT_STRIDE], s);
    }
}

__global__ void final_kernel(const float* __restrict__ partial, float* __restrict__ out) {
    __shared__ float s3[3];
    int tid = threadIdx.x;
    if (tid < 3) s3[tid] = 0.f;
    __syncthreads();
    if (tid < 3 * NSLOT) {
        float v = partial[tid * SLOT_STRIDE];
        atomicAdd(&s3[tid / NSLOT], v);
    }
    __syncthreads();
    if (tid == 0) {
        double inv = 1.0 / ((double)NN * (double)NN * 2.5066282746310002);  // N^2 * sqrt(2*pi)
        double mxx = (double)s3[0] * inv;
        double mzz = (double)s3[1] * inv;
        double mxz = (double)s3[2] * inv;
        double v = log(sqrt(mxx * mzz + 1e-5) / (mxz + 1e-5));
        out[0] = (float)v;
    }
}

extern "C" void kernel_launch(void* const* d_in, const int* in_sizes, int n_in,
                              void* d_out, int out_size, void* d_ws, size_t ws_size,
                              hipStream_t stream) {
    const float* X = (const float*)d_in[0];
    const float* Z = (const float*)d_in[1];
    char* ws = (char*)d_ws;
    __hip_bfloat16* XbF = (__hip_bfloat16*)(ws);
    __hip_bfloat16* ZbF = (__hip_bfloat16*)(ws + 1048576);
    float* na = (float*)(ws + 2097152);
    float* nb = (float*)(ws + 2097152 + 32768);
    float* partial = (float*)(ws + 2097152 + 65536);

    hipLaunchKernelGGL(prep_kernel, dim3(256), dim3(256), 0, stream,
                       X, Z, XbF, ZbF, na, nb, partial);
    hipLaunchKernelGGL(mmd_kernel, dim3(NBLOCKS), dim3(256), 0, stream, XbF, ZbF, na, nb, partial);
    hipLaunchKernelGGL(final_kernel, dim3(1), dim3(128), 0, stream, partial, (float*)d_out);
}

// Round 16
// 32.310 us; speedup vs baseline: 1.1036x; 1.1036x over previous
//
#include <hip/hip_runtime.h>
#include <hip/hip_bf16.h>
#include <math.h>

#define NN 8192
#define DD 64
// Block tile 128x64 (4 waves as 2x2 of 64x32 wave tiles), TPB=16 along bj.
#define BI_MAX 64               // block-rows (128 rows each)
#define BJ_MAX 128              // block-cols (64 cols each)
#define TRI_N 4160              // per sym combo: sum_{bi<64}(128-2bi)
#define T1B TRI_N               // end of XX
#define T2B (2*TRI_N)           // 8320: end of ZZ
#define TILES_TOTAL 16512       // 2*4160 + 64*128
#define TPB 16
#define NBLOCKS (TILES_TOTAL / TPB)   // 1032
#define NSLOT 32
#define SLOT_STRIDE 16          // floats -> 64B per slot

// Fragment-order layout: panel p = 16 source rows; chunk lane L holds
// row (p*16 + (L&15)), bf16 elems [ks*32 + (L>>4)*8, +8).
#define PANEL_ELEMS 1024        // 16 rows * 64 elems

typedef __bf16 bf16x8 __attribute__((ext_vector_type(8)));
typedef float f32x4 __attribute__((ext_vector_type(4)));

#if defined(__has_builtin)
#if __has_builtin(__builtin_amdgcn_exp2f)
#define EXP2F __builtin_amdgcn_exp2f
#endif
#endif
#ifndef EXP2F
#define EXP2F exp2f
#endif

// max3-friendly reductions (clang folds nested fmaxf to v_max3_f32)
#define FMAX3(a,b,c) fmaxf(fmaxf((a),(b)),(c))
#define FMAX4(a,b,c,d) fmaxf(FMAX3((a),(b),(c)),(d))

// ws layout:
//   [0,        1048576)  XbF bf16 [512 panels][2 ks][64 lanes][8]  (fragment order)
//   [1048576,  2097152)  ZbF bf16 same
//   [2097152, +32768)    na  f32  [8192]   ( = -log2(e) * ||x_i||^2 )
//   [+32768,  +65536)    nb  f32  [8192]
//   [+65536,  +71680)    partial f32 [3*NSLOT*SLOT_STRIDE]

__global__ __launch_bounds__(256) void prep_kernel(
        const float* __restrict__ X, const float* __restrict__ Z,
        __hip_bfloat16* __restrict__ XbF, __hip_bfloat16* __restrict__ ZbF,
        float* __restrict__ na, float* __restrict__ nb,
        float* __restrict__ partial) {
    int tid = threadIdx.x;
    int gw = blockIdx.x * 4 + (tid >> 6);    // panel index in [0, 1024)
    int lane = tid & 63;
    int lm = lane & 15, lk = lane >> 4;
    const float* src = (gw < 512) ? X : Z;
    __hip_bfloat16* dst = (gw < 512) ? XbF : ZbF;
    float* nrm = (gw < 512) ? na : nb;
    int p = (gw < 512) ? gw : gw - 512;
    int row = p * 16 + lm;

    float s = 0.f;
    #pragma unroll
    for (int ks = 0; ks < 2; ++ks) {
        const float4* q = (const float4*)(src + (size_t)row * DD + ks * 32 + lk * 8);
        float4 u = q[0], v = q[1];
        float w[8] = {u.x, u.y, u.z, u.w, v.x, v.y, v.z, v.w};
        unsigned int h[8];
        #pragma unroll
        for (int r = 0; r < 8; ++r) {
            __hip_bfloat16 b = __float2bfloat16(w[r]);
            h[r] = *(unsigned short*)&b;
            float xr = __bfloat162float(b);
            s = fmaf(xr, xr, s);
        }
        uint4 pk;
        pk.x = h[0] | (h[1] << 16); pk.y = h[2] | (h[3] << 16);
        pk.z = h[4] | (h[5] << 16); pk.w = h[6] | (h[7] << 16);
        *(uint4*)(dst + (size_t)p * PANEL_ELEMS + ks * 512 + lane * 8) = pk;
    }
    s += __shfl_xor(s, 16, 64);
    s += __shfl_xor(s, 32, 64);
    if (lk == 0) nrm[row] = -1.4426950408889634f * s;

    if (blockIdx.x == 0) {
        for (int i = tid; i < 3 * NSLOT * SLOT_STRIDE; i += 256) partial[i] = 0.f;
    }
}

// R14's structure (depth-1 dbuf, proven best) + three VALU-chain micro-opts:
// (1) max3-shaped gate trees (v_max3_f32, ~20 ops vs 31, shallower deps);
// (2) s_setprio(1) around MFMA+gate (independent barrier-free waves -- the
//     regime where setprio measured +4-7%);
// (3) __launch_bounds__(256,3) pins the measured 3-waves/SIMD occupancy.
__global__ __launch_bounds__(256, 3) void mmd_kernel(
        const __hip_bfloat16* __restrict__ XbFh, const __hip_bfloat16* __restrict__ ZbFh,
        const float* __restrict__ na, const float* __restrict__ nb,
        float* __restrict__ partial) {
    int tid = threadIdx.x;
    int wave = tid >> 6, lane = tid & 63;
    int wr = wave >> 1, wc = wave & 1;
    int lm = lane & 15;   // frag row (within 16) / C col
    int lk = lane >> 4;   // k-group of 8 / C row group of 4
    __shared__ float wsum[4];
    const float C2 = 2.8853900817779268f;  // 2*log2(e)

    // ---- map block's first tile (once) ----
    int t0 = blockIdx.x * TPB;
    int combo, bi, bj;
    if (t0 < T2B) {
        combo = (t0 < T1B) ? 0 : 1;
        int tt = t0 - (combo ? T1B : 0);
        int rr = (int)((129.0f - sqrtf(16641.0f - 4.0f * (float)tt)) * 0.5f);
        rr = rr < 0 ? 0 : (rr > 63 ? 63 : rr);
        while (rr > 0 && rr * (129 - rr) > tt) --rr;
        while ((rr + 1) * (128 - rr) <= tt) ++rr;
        bi = rr;
        bj = 2 * rr + (tt - rr * (129 - rr));
    } else {
        combo = 2;
        int rem = t0 - T2B;
        bi = rem >> 7;
        bj = rem & 127;
    }
    const bool sym = (combo != 2);
    const __bf16 *A, *B;
    const float *sa, *sb;
    const __bf16* XbF = (const __bf16*)XbFh;
    const __bf16* ZbF = (const __bf16*)ZbFh;
    if (combo == 0)      { A = XbF; B = XbF; sa = na; sb = na; }
    else if (combo == 1) { A = ZbF; B = ZbF; sa = nb; sb = nb; }
    else                 { A = XbF; B = ZbF; sa = na; sb = nb; }

    // ---- A fragments + row norms for current bi ----
    bf16x8 af[2][4];
    float nav[4][4], navrtmax[4], navmax;
    {
        int pA = bi * 8 + wr * 4;
        #pragma unroll
        for (int ks = 0; ks < 2; ++ks)
            #pragma unroll
            for (int rt = 0; rt < 4; ++rt)
                af[ks][rt] = *(const bf16x8*)(A + (size_t)(pA + rt) * PANEL_ELEMS + ks * 512 + lane * 8);
        int row0 = bi * 128 + wr * 64;
        #pragma unroll
        for (int rt = 0; rt < 4; ++rt) {
            #pragma unroll
            for (int r = 0; r < 4; ++r) nav[rt][r] = sa[row0 + rt * 16 + lk * 4 + r];
            navrtmax[rt] = FMAX4(nav[rt][0], nav[rt][1], nav[rt][2], nav[rt][3]);
        }
        navmax = FMAX4(navrtmax[0], navrtmax[1], navrtmax[2], navrtmax[3]);
    }

    // ---- prefetch B for first tile (32 cols: panels bj*4+wc*2+ct, ct<2) ----
    bf16x8 bufB[2][2][2];   // [buf][ks][ct]
    float bufNb[2][2];
    {
        int pB = bj * 4 + wc * 2;
        #pragma unroll
        for (int ks = 0; ks < 2; ++ks)
            #pragma unroll
            for (int ct = 0; ct < 2; ++ct)
                bufB[0][ks][ct] = *(const bf16x8*)(B + (size_t)(pB + ct) * PANEL_ELEMS + ks * 512 + lane * 8);
        int col0 = bj * 64 + wc * 32;
        #pragma unroll
        for (int ct = 0; ct < 2; ++ct) bufNb[0][ct] = sb[col0 + ct * 16 + lm];
    }

    float lsum = 0.f;

    #pragma unroll
    for (int it = 0; it < TPB; ++it) {
        const int cur = it & 1, nxt = cur ^ 1;
        const bool last = (it + 1 == TPB);
        int row0 = bi * 128 + wr * 64;
        int col0 = bj * 64 + wc * 32;
        bool above = sym && (col0 >= row0 + 64);     // whole tile strictly above diag
        bool elemw = sym && !above;                  // per-element weights
        float tileScale = above ? 2.f : 1.f;

        // next tile coords + B prefetch (independent of current tile's data)
        int nbi = bi, nbj = bj;
        if (!last) {
            nbj = bj + 1;
            if (nbj == BJ_MAX) { nbi = bi + 1; nbj = sym ? 2 * nbi : 0; }
            int npB = nbj * 4 + wc * 2;
            #pragma unroll
            for (int ks = 0; ks < 2; ++ks)
                #pragma unroll
                for (int ct = 0; ct < 2; ++ct)
                    bufB[nxt][ks][ct] = *(const bf16x8*)(B + (size_t)(npB + ct) * PANEL_ELEMS + ks * 512 + lane * 8);
            int ncol0 = nbj * 64 + wc * 32;
            #pragma unroll
            for (int ct = 0; ct < 2; ++ct) bufNb[nxt][ct] = sb[ncol0 + ct * 16 + lm];
        }
        // Fence: prefetch loads must ISSUE here, before the MFMA cluster.
        __builtin_amdgcn_sched_barrier(0);

        // ---- MFMA + gate, wave-priority boosted ----
        __builtin_amdgcn_s_setprio(1);
        f32x4 acc[4][2] = {};
        #pragma unroll
        for (int ks = 0; ks < 2; ++ks)
            #pragma unroll
            for (int rt = 0; rt < 4; ++rt)
                #pragma unroll
                for (int ct = 0; ct < 2; ++ct)
                    acc[rt][ct] = __builtin_amdgcn_mfma_f32_16x16x32_bf16(
                        af[ks][rt], bufB[cur][ks][ct], acc[rt][ct], 0, 0, 0);

        // ---- tile-level gate (max3-shaped): one branch for closed tiles ----
        float m00 = FMAX4(acc[0][0][0], acc[0][0][1], acc[0][0][2], acc[0][0][3]);
        float m01 = FMAX4(acc[0][1][0], acc[0][1][1], acc[0][1][2], acc[0][1][3]);
        float m10 = FMAX4(acc[1][0][0], acc[1][0][1], acc[1][0][2], acc[1][0][3]);
        float m11 = FMAX4(acc[1][1][0], acc[1][1][1], acc[1][1][2], acc[1][1][3]);
        float m20 = FMAX4(acc[2][0][0], acc[2][0][1], acc[2][0][2], acc[2][0][3]);
        float m21 = FMAX4(acc[2][1][0], acc[2][1][1], acc[2][1][2], acc[2][1][3]);
        float m30 = FMAX4(acc[3][0][0], acc[3][0][1], acc[3][0][2], acc[3][0][3]);
        float m31 = FMAX4(acc[3][1][0], acc[3][1][1], acc[3][1][2], acc[3][1][3]);
        float gmax = fmaxf(FMAX4(m00, m01, m10, m11), FMAX4(m20, m21, m30, m31));
        __builtin_amdgcn_s_setprio(0);
        float nbmax = fmaxf(bufNb[cur][0], bufNb[cur][1]);
        float tileBound = fmaf(gmax, C2, navmax + nbmax);
        if (__any(tileBound > -30.f)) {
            // ---- per-frag gated epilogue (rare: diag-adjacent tiles) ----
            #pragma unroll
            for (int rt = 0; rt < 4; ++rt) {
                #pragma unroll
                for (int ct = 0; ct < 2; ++ct) {
                    float fm = FMAX4(acc[rt][ct][0], acc[rt][ct][1], acc[rt][ct][2], acc[rt][ct][3]);
                    float fb = fmaf(fm, C2, navrtmax[rt] + bufNb[cur][ct]);
                    if (__any(fb > -30.f)) {
                        float base = bufNb[cur][ct];
                        float a0 = fmaf(acc[rt][ct][0], C2, nav[rt][0] + base);
                        float a1 = fmaf(acc[rt][ct][1], C2, nav[rt][1] + base);
                        float a2 = fmaf(acc[rt][ct][2], C2, nav[rt][2] + base);
                        float a3 = fmaf(acc[rt][ct][3], C2, nav[rt][3] + base);
                        float e0 = EXP2F(fminf(a0, 0.f));
                        float e1 = EXP2F(fminf(a1, 0.f));
                        float e2 = EXP2F(fminf(a2, 0.f));
                        float e3 = EXP2F(fminf(a3, 0.f));
                        if (elemw) {
                            int gcol = col0 + ct * 16 + lm;
                            int gr = row0 + rt * 16 + lk * 4;
                            e0 *= (gr + 0 < gcol) ? 2.f : ((gr + 0 == gcol) ? 1.f : 0.f);
                            e1 *= (gr + 1 < gcol) ? 2.f : ((gr + 1 == gcol) ? 1.f : 0.f);
                            e2 *= (gr + 2 < gcol) ? 2.f : ((gr + 2 == gcol) ? 1.f : 0.f);
                            e3 *= (gr + 3 < gcol) ? 2.f : ((gr + 3 == gcol) ? 1.f : 0.f);
                            lsum += (e0 + e1) + (e2 + e3);
                        } else {
                            lsum += tileScale * ((e0 + e1) + (e2 + e3));
                        }
                    }
                }
            }
        }

        // ---- row change: reload A (after epilogue consumed nav) ----
        if (!last && nbi != bi) {
            int npA = nbi * 8 + wr * 4;
            #pragma unroll
            for (int ks = 0; ks < 2; ++ks)
                #pragma unroll
                for (int rt = 0; rt < 4; ++rt)
                    af[ks][rt] = *(const bf16x8*)(A + (size_t)(npA + rt) * PANEL_ELEMS + ks * 512 + lane * 8);
            int nrow0 = nbi * 128 + wr * 64;
            #pragma unroll
            for (int rt = 0; rt < 4; ++rt) {
                #pragma unroll
                for (int r = 0; r < 4; ++r) nav[rt][r] = sa[nrow0 + rt * 16 + lk * 4 + r];
                navrtmax[rt] = FMAX4(nav[rt][0], nav[rt][1], nav[rt][2], nav[rt][3]);
            }
            navmax = FMAX4(navrtmax[0], navrtmax[1], navrtmax[2], navrtmax[3]);
            __builtin_amdgcn_sched_barrier(0);
        }
        bi = nbi; bj = nbj;
    }

    // ---- single flush, spread over cache-line slots ----
    #pragma unroll
    for (int off = 32; off; off >>= 1) lsum += __shfl_xor(lsum, off, 64);
    if (lane == 0) wsum[wave] = lsum;
    __syncthreads();
    if (tid == 0) {
        float s = (wsum[0] + wsum[1]) + (wsum[2] + wsum[3]);
        int slot = combo * NSLOT + (blockIdx.x & (NSLOT - 1));
        atomicAdd(&partial[slot * SLOT_STRIDE], s);
    }
}

__global__ void final_kernel(const float* __restrict__ partial, float* __restrict__ out) {
    __shared__ float s3[3];
    int tid = threadIdx.x;
    if (tid < 3) s3[tid] = 0.f;
    __syncthreads();
    if (tid < 3 * NSLOT) {
        float v = partial[tid * SLOT_STRIDE];
        atomicAdd(&s3[tid / NSLOT], v);
    }
    __syncthreads();
    if (tid == 0) {
        double inv = 1.0 / ((double)NN * (double)NN * 2.5066282746310002);  // N^2 * sqrt(2*pi)
        double mxx = (double)s3[0] * inv;
        double mzz = (double)s3[1] * inv;
        double mxz = (double)s3[2] * inv;
        double v = log(sqrt(mxx * mzz + 1e-5) / (mxz + 1e-5));
        out[0] = (float)v;
    }
}

extern "C" void kernel_launch(void* const* d_in, const int* in_sizes, int n_in,
                              void* d_out, int out_size, void* d_ws, size_t ws_size,
                              hipStream_t stream) {
    const float* X = (const float*)d_in[0];
    const float* Z = (const float*)d_in[1];
    char* ws = (char*)d_ws;
    __hip_bfloat16* XbF = (__hip_bfloat16*)(ws);
    __hip_bfloat16* ZbF = (__hip_bfloat16*)(ws + 1048576);
    float* na = (float*)(ws + 2097152);
    float* nb = (float*)(ws + 2097152 + 32768);
    float* partial = (float*)(ws + 2097152 + 65536);

    hipLaunchKernelGGL(prep_kernel, dim3(256), dim3(256), 0, stream,
                       X, Z, XbF, ZbF, na, nb, partial);
    hipLaunchKernelGGL(mmd_kernel, dim3(NBLOCKS), dim3(256), 0, stream, XbF, ZbF, na, nb, partial);
    hipLaunchKernelGGL(final_kernel, dim3(1), dim3(128), 0, stream, partial, (float*)d_out);
}